// Round 4
// baseline (468.535 us; speedup 1.0000x reference)
//
#include <hip/hip_runtime.h>
#include <hip/hip_bf16.h>
#include <stdint.h>

#define M_TOT 16384     // B*P = 64*256
#define DM 768
#define BM 256
#define BN 192
#define NKT3 12         // K / 64
#define QOFF (128 * DM) // sumsq offset in bnpart (floats)

typedef __attribute__((ext_vector_type(4))) float f32x4;
typedef __attribute__((ext_vector_type(8))) short short8;
typedef __attribute__((ext_vector_type(4))) unsigned short ushort4v;

__device__ __forceinline__ unsigned short f2bf(float f) {
    union { float f; unsigned u; } v; v.f = f;
    unsigned r = v.u + 0x7fffu + ((v.u >> 16) & 1u);
    return (unsigned short)(r >> 16);
}
__device__ __forceinline__ float bf2f(unsigned short h) {
    union { unsigned u; float f; } v; v.u = ((unsigned)h) << 16;
    return v.f;
}

__device__ __forceinline__ void gload_lds16(const unsigned short* g, unsigned short* l) {
    __builtin_amdgcn_global_load_lds(
        (const __attribute__((address_space(1))) void*)g,
        (__attribute__((address_space(3))) void*)l, 16, 0, 0);
}

// ---------------- prep: weight cvt + inverse permutation + barrier counters ----------------
__global__ __launch_bounds__(256)
void prep(const float* __restrict__ cw, const float* __restrict__ w1,
          const float* __restrict__ mw, const int* __restrict__ perm,
          unsigned short* __restrict__ wA, unsigned short* __restrict__ wD,
          unsigned short* __restrict__ wM, int* __restrict__ invp,
          unsigned int* __restrict__ cnt)
{
    int b = blockIdx.x;
    if (b < 2880) {
        int i = b * 256 + threadIdx.x;          // 737280 vec4 groups total
        const float* src; unsigned short* dst; int off;
        if (i < 147456)              { src = cw; dst = wA; off = i; }
        else if (i < 147456+442368)  { src = w1; dst = wD; off = i - 147456; }
        else                         { src = mw; dst = wM; off = i - 589824; }
        f32x4 v = ((const f32x4*)src)[off];
        ushort4v o;
        o.x = f2bf(v.x); o.y = f2bf(v.y); o.z = f2bf(v.z); o.w = f2bf(v.w);
        ((ushort4v*)dst)[off] = o;
    } else if (b < 2944) {
        int i = (b - 2880) * 256 + threadIdx.x;  // 16384
        int bb = i >> 8;
        invp[(bb << 8) + perm[i]] = i & 255;
    } else {
        if (threadIdx.x < 3) cnt[threadIdx.x] = 0u;
    }
}

// ---------------- im2col: x[B,3,256,256] -> patches[16384,768] bf16 ----------------
__global__ __launch_bounds__(256)
void im2col(const float* __restrict__ x, unsigned short* __restrict__ patches)
{
    int t = blockIdx.x * 256 + threadIdx.x;     // 3,145,728 total (4 floats each)
    int bp = t / 192;
    int q  = t - bp * 192;
    int c   = q >> 6;
    int kh  = (q >> 2) & 15;
    int kw0 = (q & 3) << 2;
    int b = bp >> 8, p = bp & 255;
    int ph = p >> 4, pw = p & 15;
    const float* src = x + ((((size_t)b * 3 + c) * 256 + ph * 16 + kh) * 256 + pw * 16 + kw0);
    f32x4 v = *(const f32x4*)src;
    ushort4v o;
    o.x = f2bf(v.x); o.y = f2bf(v.y); o.z = f2bf(v.z); o.w = f2bf(v.w);
    *(ushort4v*)(patches + (size_t)bp * DM + (q << 2)) = o;
}

// =====================================================================
// GEMM: out[M,768] = A[M,768] * Bw[768,768]^T + bias
// BM=256 x BN=192, BK=64, 8 waves (2M x 4N), wave tile 128x48.
// 3-deep A buffer, 2-deep B, T2 swizzle, counted vmcnt(4), T5 setprio.
// EPI 0: relu->bf16
// EPI 1: fused BN: grid-barrier -> stats -> apply(+POS:pos+relu) -> bf16 in-place
// EPI 2: perm-scatter->f32
// =====================================================================
#define VM4  asm volatile("s_waitcnt vmcnt(4)" ::: "memory");
#define VM0  asm volatile("s_waitcnt vmcnt(0)" ::: "memory");
#define BARR asm volatile("s_barrier" ::: "memory");
#define NOVM

#define DO_PHASE(AB, BB, MH, KS, LOADB, VMC, ...)                                \
  {                                                                              \
    if (LOADB) {                                                                 \
      _Pragma("unroll")                                                          \
      for (int j = 0; j < 3; ++j)                                                \
        breg[j] = *(const short8*)((const char*)Bb[BB] +                         \
                  (wc * 48 + j * 16 + frow) * 128 + (((KS) * 64 + fq16) ^ rswz));\
    }                                                                            \
    short8 af[4];                                                                \
    _Pragma("unroll")                                                            \
    for (int i = 0; i < 4; ++i)                                                  \
      af[i] = *(const short8*)((const char*)Aa[AB] +                             \
              (wr * 128 + (MH) * 64 + i * 16 + frow) * 128 +                     \
              (((KS) * 64 + fq16) ^ rswz));                                      \
    __VA_ARGS__;                                                                 \
    __builtin_amdgcn_s_setprio(1);                                               \
    _Pragma("unroll")                                                            \
    for (int i = 0; i < 4; ++i)                                                  \
      _Pragma("unroll")                                                          \
      for (int j = 0; j < 3; ++j)                                                \
        acc[(MH) * 4 + i][j] = __builtin_amdgcn_mfma_f32_16x16x32_bf16(          \
            af[i], breg[j], acc[(MH) * 4 + i][j], 0, 0, 0);                      \
    __builtin_amdgcn_s_setprio(0);                                               \
    VMC                                                                          \
    BARR                                                                         \
  }

template<int EPI, int POS>
__global__ __launch_bounds__(512, 2)
void gemm8p(const unsigned short* __restrict__ A,
            const unsigned short* __restrict__ Bw,
            const float* __restrict__ bias,
            void* __restrict__ outp,
            const int* __restrict__ invp,
            float* __restrict__ bnpart,
            const float* __restrict__ gamma,
            const float* __restrict__ beta,
            const float* __restrict__ pos,
            unsigned int* __restrict__ cnt)
{
    __shared__ unsigned short Aa[3][BM * 64];   // 3 x 32 KB
    __shared__ unsigned short Bb[2][BN * 64];   // 2 x 24 KB  (total 144 KB -> 1 block/CU)

    const int tid  = threadIdx.x;
    const int w    = tid >> 6;
    const int lane = tid & 63;
    const int wr = w >> 2, wc = w & 3;

    // bijective XCD swizzle over exactly 256 workgroups (32 per XCD)
    int bid = blockIdx.x;
    int nb  = (bid & 7) * 32 + (bid >> 3);
    const int tileM = nb >> 2, tileN = nb & 3;
    const int m0 = tileM * BM, n0 = tileN * BN;

    // ---- staging addressing (linear LDS dest + inverse-swizzled global src) ----
    const int sRow = lane >> 3;
    const int swzc = ((lane & 7) * 16) ^ ((sRow & 7) << 4);
    const unsigned short* gA0 = A  + (size_t)(m0 + w * 32 + sRow) * DM + (swzc >> 1);
    const unsigned short* gB0 = Bw + (size_t)(n0 + w * 24 + sRow) * DM + (swzc >> 1);

    auto STAGE_A = [&](int buf, int kt) {
        #pragma unroll
        for (int j = 0; j < 4; ++j)
            gload_lds16(gA0 + (size_t)j * 8 * DM + kt * 64,
                        &Aa[buf][(w * 32 + j * 8) * 64]);
    };
    auto STAGE_B = [&](int buf, int kt) {
        #pragma unroll
        for (int j = 0; j < 3; ++j)
            gload_lds16(gB0 + (size_t)j * 8 * DM + kt * 64,
                        &Bb[buf][(w * 24 + j * 8) * 64]);
    };

    const int frow = lane & 15;
    const int fq16 = (lane >> 4) * 16;
    const int rswz = (lane & 7) << 4;

    f32x4 acc[8][3] = {};
    short8 breg[3];

    // ---- prologue: A(0)->a0, B(0)->b0, A(1)->a1 ----
    STAGE_A(0, 0);
    STAGE_B(0, 0);
    STAGE_A(1, 1);
    VM4
    BARR

    #pragma unroll
    for (int kt = 0; kt < NKT3; ++kt) {
        const int ab = kt % 3, bb = kt & 1;
        DO_PHASE(ab, bb, 0, 0, 1, NOVM, if (kt < 11) STAGE_B((kt + 1) & 1, kt + 1))
        DO_PHASE(ab, bb, 1, 0, 0, NOVM, if (kt < 10) STAGE_A((kt + 2) % 3, kt + 2))
        DO_PHASE(ab, bb, 0, 1, 1, NOVM, )
        if (kt < 10)       { DO_PHASE(ab, bb, 1, 1, 0, VM4, ) }
        else if (kt == 10) { DO_PHASE(ab, bb, 1, 1, 0, VM0, ) }
        else               { DO_PHASE(ab, bb, 1, 1, 0, NOVM, ) }
    }

    // ---- epilogue ----
    const int crow = (lane >> 4) * 4;
    const int ccol = lane & 15;
    const int nbase = n0 + wc * 48;

    float bv[3];
    #pragma unroll
    for (int j = 0; j < 3; ++j) bv[j] = bias[nbase + j * 16 + ccol];

    if (EPI == 0) {
        unsigned short* O = (unsigned short*)outp;
        #pragma unroll
        for (int mi = 0; mi < 8; ++mi) {
            #pragma unroll
            for (int r = 0; r < 4; ++r) {
                int m = m0 + wr * 128 + mi * 16 + crow + r;
                unsigned short* orow = O + (size_t)m * DM + nbase + ccol;
                #pragma unroll
                for (int j = 0; j < 3; ++j)
                    orow[j * 16] = f2bf(fmaxf(acc[mi][j][r] + bv[j], 0.0f));
            }
        }
    }

    if (EPI == 2) {
        float* O = (float*)outp;
        #pragma unroll
        for (int mi = 0; mi < 8; ++mi) {
            #pragma unroll
            for (int r = 0; r < 4; ++r) {
                int m = m0 + wr * 128 + mi * 16 + crow + r;
                int mo = (m & ~255) | invp[m];
                float* orow = O + (size_t)mo * DM + nbase + ccol;
                #pragma unroll
                for (int j = 0; j < 3; ++j)
                    orow[j * 16] = acc[mi][j][r] + bv[j];
            }
        }
    }

    if (EPI == 1) {
        // ---- deterministic BN column partials (this wave: 128 rows x 48 cols) ----
        #pragma unroll
        for (int j = 0; j < 3; ++j) {
            float s = 0.f, q = 0.f;
            #pragma unroll
            for (int mi = 0; mi < 8; ++mi)
                #pragma unroll
                for (int r = 0; r < 4; ++r) {
                    float v = acc[mi][j][r] + bv[j];
                    s += v; q += v * v;
                }
            s += __shfl_xor(s, 16); s += __shfl_xor(s, 32);
            q += __shfl_xor(q, 16); q += __shfl_xor(q, 32);
            if (lane < 16) {
                int c  = nbase + j * 16 + lane;
                int ri = tileM * 2 + wr;
                bnpart[(size_t)c * 128 + ri]        = s;
                bnpart[QOFF + (size_t)c * 128 + ri] = q;
            }
        }

        // ---- grid barrier (256 blocks, all co-resident: 144KB LDS -> 1 block/CU) ----
        __threadfence();
        __syncthreads();
        if (tid == 0) {
            __hip_atomic_fetch_add(cnt, 1u, __ATOMIC_ACQ_REL, __HIP_MEMORY_SCOPE_AGENT);
            while (__hip_atomic_load(cnt, __ATOMIC_ACQUIRE, __HIP_MEMORY_SCOPE_AGENT) < 256u) {}
        }
        __syncthreads();
        __threadfence();

        // ---- finalize scale/shift for this block's 192 columns (into LDS) ----
        float* scl = (float*)&Aa[0][0];
        float* shf = scl + 192;
        if (tid < 192) {
            int c = n0 + tid;
            const float* ps = bnpart + (size_t)c * 128;
            const float* pq = bnpart + QOFF + (size_t)c * 128;
            float s = 0.f, q = 0.f;
            #pragma unroll 8
            for (int i = 0; i < 128; ++i) { s += ps[i]; q += pq[i]; }
            float mu  = s * (1.0f / 16384.0f);
            float var = q * (1.0f / 16384.0f) - mu * mu;
            float sc_ = rsqrtf(var + 1e-5f) * gamma[c];
            scl[tid] = sc_;
            shf[tid] = beta[c] - mu * sc_;
        }
        __syncthreads();

        // ---- apply BN (+pos+relu for POS) from live accumulators, write in-place ----
        unsigned short* O = (unsigned short*)outp;
        #pragma unroll
        for (int mi = 0; mi < 8; ++mi) {
            #pragma unroll
            for (int r = 0; r < 4; ++r) {
                int m = m0 + wr * 128 + mi * 16 + crow + r;
                unsigned short* orow = O + (size_t)m * DM + nbase + ccol;
                #pragma unroll
                for (int j = 0; j < 3; ++j) {
                    int ci = wc * 48 + j * 16 + ccol;
                    float y = fmaxf(scl[ci] * (acc[mi][j][r] + bv[j]) + shf[ci], 0.0f);
                    if (POS) y = fmaxf(y + pos[(m & 255) * DM + n0 + ci], 0.0f);
                    orow[j * 16] = f2bf(y);
                }
            }
        }
    }
}

extern "C" void kernel_launch(void* const* d_in, const int* in_sizes, int n_in,
                              void* d_out, int out_size, void* d_ws, size_t ws_size,
                              hipStream_t stream)
{
    (void)in_sizes; (void)n_in; (void)out_size; (void)ws_size;

    const float* x       = (const float*)d_in[0];
    const float* conv0_w = (const float*)d_in[1];
    const float* conv0_b = (const float*)d_in[2];
    const float* w1      = (const float*)d_in[3];
    const float* b1      = (const float*)d_in[4];
    const float* gamma   = (const float*)d_in[5];
    const float* beta    = (const float*)d_in[6];
    const float* pos     = (const float*)d_in[7];
    const float* mixer_w = (const float*)d_in[8];
    const float* mixer_b = (const float*)d_in[9];
    const int*   perm    = (const int*)d_in[10];

    // workspace layout (~53 MB)
    unsigned short* actA = (unsigned short*)d_ws;               // 16384*768 bf16 (patches)
    unsigned short* actB = actA + (size_t)M_TOT * DM;           // 16384*768 bf16 (activations)
    unsigned short* wA   = actB + (size_t)M_TOT * DM;           // 768*768
    unsigned short* wD   = wA + DM * DM;                        // 3*768*768
    unsigned short* wM   = wD + 3 * DM * DM;                    // 768*768
    float* bnpart = (float*)(wM + DM * DM);                     // 2*128*768 f32
    unsigned int* cnts = (unsigned int*)(bnpart + 2 * 128 * DM);// 3
    int*   invp   = (int*)(cnts + 4);                           // 16384

    prep<<<2945, 256, 0, stream>>>(conv0_w, w1, mixer_w, perm, wA, wD, wM, invp, cnts);
    im2col<<<12288, 256, 0, stream>>>(x, actA);

    // patch embed: relu(patches @ conv0_w^T + b) -> actB
    gemm8p<0, 0><<<256, 512, 0, stream>>>(actA, wA, conv0_b, actB, nullptr,
                                          nullptr, nullptr, nullptr, nullptr, nullptr);

    // 3x (1x1 conv -> BN -> ReLU), fused, in-place on actB; d=2 adds pos+relu
    gemm8p<1, 0><<<256, 512, 0, stream>>>(actB, wD + 0 * (size_t)DM * DM, b1 + 0 * DM, actB,
                                          nullptr, bnpart, gamma + 0 * DM, beta + 0 * DM,
                                          pos, cnts + 0);
    gemm8p<1, 0><<<256, 512, 0, stream>>>(actB, wD + 1 * (size_t)DM * DM, b1 + 1 * DM, actB,
                                          nullptr, bnpart, gamma + 1 * DM, beta + 1 * DM,
                                          pos, cnts + 1);
    gemm8p<1, 1><<<256, 512, 0, stream>>>(actB, wD + 2 * (size_t)DM * DM, b1 + 2 * DM, actB,
                                          nullptr, bnpart, gamma + 2 * DM, beta + 2 * DM,
                                          pos, cnts + 2);

    // mixer + per-sample permutation scatter to fp32 output
    gemm8p<2, 0><<<256, 512, 0, stream>>>(actB, wM, mixer_b, d_out, invp,
                                          nullptr, nullptr, nullptr, nullptr, nullptr);
}

// Round 5
// 211.954 us; speedup vs baseline: 2.2105x; 2.2105x over previous
//
#include <hip/hip_runtime.h>
#include <hip/hip_bf16.h>
#include <stdint.h>

#define M_TOT 16384     // B*P = 64*256
#define DM 768
#define BM 256
#define BN 192
#define NKT3 12         // K / 64
#define QOFF (128 * DM) // sumsq offset in bnpart (floats)

typedef __attribute__((ext_vector_type(4))) float f32x4;
typedef __attribute__((ext_vector_type(8))) short short8;
typedef __attribute__((ext_vector_type(8))) unsigned short ushort8;
typedef __attribute__((ext_vector_type(4))) unsigned short ushort4v;

__device__ __forceinline__ unsigned short f2bf(float f) {
    union { float f; unsigned u; } v; v.f = f;
    unsigned r = v.u + 0x7fffu + ((v.u >> 16) & 1u);
    return (unsigned short)(r >> 16);
}
__device__ __forceinline__ float bf2f(unsigned short h) {
    union { unsigned u; float f; } v; v.u = ((unsigned)h) << 16;
    return v.f;
}

__device__ __forceinline__ void gload_lds16(const unsigned short* g, unsigned short* l) {
    __builtin_amdgcn_global_load_lds(
        (const __attribute__((address_space(1))) void*)g,
        (__attribute__((address_space(3))) void*)l, 16, 0, 0);
}

// ---------------- prep: weight cvt + inverse permutation ----------------
__global__ __launch_bounds__(256)
void prep(const float* __restrict__ cw, const float* __restrict__ w1,
          const float* __restrict__ mw, const int* __restrict__ perm,
          unsigned short* __restrict__ wA, unsigned short* __restrict__ wD,
          unsigned short* __restrict__ wM, int* __restrict__ invp)
{
    int b = blockIdx.x;
    if (b < 2880) {
        int i = b * 256 + threadIdx.x;          // 737280 vec4 groups total
        const float* src; unsigned short* dst; int off;
        if (i < 147456)              { src = cw; dst = wA; off = i; }
        else if (i < 147456+442368)  { src = w1; dst = wD; off = i - 147456; }
        else                         { src = mw; dst = wM; off = i - 589824; }
        f32x4 v = ((const f32x4*)src)[off];
        ushort4v o;
        o.x = f2bf(v.x); o.y = f2bf(v.y); o.z = f2bf(v.z); o.w = f2bf(v.w);
        ((ushort4v*)dst)[off] = o;
    } else {
        int i = (b - 2880) * 256 + threadIdx.x;  // 16384
        int bb = i >> 8;
        invp[(bb << 8) + perm[i]] = i & 255;
    }
}

// ---------------- im2col: x[B,3,256,256] -> patches[16384,768] bf16 ----------------
__global__ __launch_bounds__(256)
void im2col(const float* __restrict__ x, unsigned short* __restrict__ patches)
{
    int t = blockIdx.x * 256 + threadIdx.x;     // 3,145,728 total (4 floats each)
    int bp = t / 192;
    int q  = t - bp * 192;
    int c   = q >> 6;
    int kh  = (q >> 2) & 15;
    int kw0 = (q & 3) << 2;
    int b = bp >> 8, p = bp & 255;
    int ph = p >> 4, pw = p & 15;
    const float* src = x + ((((size_t)b * 3 + c) * 256 + ph * 16 + kh) * 256 + pw * 16 + kw0);
    f32x4 v = *(const f32x4*)src;
    ushort4v o;
    o.x = f2bf(v.x); o.y = f2bf(v.y); o.z = f2bf(v.z); o.w = f2bf(v.w);
    *(ushort4v*)(patches + (size_t)bp * DM + (q << 2)) = o;
}

// =====================================================================
// GEMM: out[M,768] = T(A)[M,768] * Bw[768,768]^T + bias
//   T = identity            (BNA=0, A staged via global_load_lds)
//   T = relu(scl*a+shf)     (BNA=1, reg-staged, fused BN apply)
//   T = relu(relu(scl*a+shf)+pos) (BNA=2, mixer input)
// BM=256 x BN=192, BK=64, 8 waves (2M x 4N), wave tile 128x48.
// EPI 0: relu->bf16 ; EPI 1: ->bf16 + BN column partials ; EPI 2: perm-scatter->f32
// =====================================================================
#define VM4  asm volatile("s_waitcnt vmcnt(4)" ::: "memory");
#define VM0  asm volatile("s_waitcnt vmcnt(0)" ::: "memory");
#define LGKM0 asm volatile("s_waitcnt lgkmcnt(0)" ::: "memory");
#define BARR asm volatile("s_barrier" ::: "memory");

// phase: [opt B-frag loads] + A-frag loads + PRE + MFMA(12) + POST + barrier
#define PH(AB, BB, MH, KS, LOADB, PRE, POST)                                     \
  {                                                                              \
    if (LOADB) {                                                                 \
      _Pragma("unroll")                                                          \
      for (int j = 0; j < 3; ++j)                                                \
        breg[j] = *(const short8*)((const char*)Bb + (size_t)(BB) * (BN*64*2) +  \
                  (wc * 48 + j * 16 + frow) * 128 + (((KS) * 64 + fq16) ^ rswz));\
    }                                                                            \
    short8 af[4];                                                                \
    _Pragma("unroll")                                                            \
    for (int i = 0; i < 4; ++i)                                                  \
      af[i] = *(const short8*)((const char*)Aa + (size_t)(AB) * (BM*64*2) +      \
              (wr * 128 + (MH) * 64 + i * 16 + frow) * 128 +                     \
              (((KS) * 64 + fq16) ^ rswz));                                      \
    PRE;                                                                         \
    __builtin_amdgcn_s_setprio(1);                                               \
    _Pragma("unroll")                                                            \
    for (int i = 0; i < 4; ++i)                                                  \
      _Pragma("unroll")                                                          \
      for (int j = 0; j < 3; ++j)                                                \
        acc[(MH) * 4 + i][j] = __builtin_amdgcn_mfma_f32_16x16x32_bf16(          \
            af[i], breg[j], acc[(MH) * 4 + i][j], 0, 0, 0);                      \
    __builtin_amdgcn_s_setprio(0);                                               \
    POST;                                                                        \
    BARR                                                                         \
  }

template<int EPI, int BNA>
__global__ __launch_bounds__(512, 2)
void gemm8p(const unsigned short* __restrict__ A,
            const unsigned short* __restrict__ Bw,
            const float* __restrict__ bias,
            void* __restrict__ outp,
            const int* __restrict__ invp,
            float* __restrict__ bnpart,
            const float* __restrict__ ssA,     // [scale 768 | shift 768] for A transform
            const float* __restrict__ pos)     // [256][768] (BNA==2 only)
{
    __shared__ unsigned short Aa[3][BM * 64];   // 3 x 32 KB
    __shared__ unsigned short Bb[2][BN * 64];   // 2 x 24 KB  (total 144 KB -> 1 block/CU)

    const int tid  = threadIdx.x;
    const int w    = tid >> 6;
    const int lane = tid & 63;
    const int wr = w >> 2, wc = w & 3;

    // bijective XCD swizzle over exactly 256 workgroups (32 per XCD)
    int bid = blockIdx.x;
    int nb  = (bid & 7) * 32 + (bid >> 3);
    const int tileM = nb >> 2, tileN = nb & 3;
    const int m0 = tileM * BM, n0 = tileN * BN;

    // ---- gload_lds staging (linear LDS dest + inverse-swizzled global src) ----
    const int sRow = lane >> 3;
    const int swzc = ((lane & 7) * 16) ^ ((sRow & 7) << 4);
    const unsigned short* gA0 = A  + (size_t)(m0 + w * 32 + sRow) * DM + (swzc >> 1);
    const unsigned short* gB0 = Bw + (size_t)(n0 + w * 24 + sRow) * DM + (swzc >> 1);

    auto STAGE_A = [&](int buf, int kt) {
        #pragma unroll
        for (int j = 0; j < 4; ++j)
            gload_lds16(gA0 + (size_t)j * 8 * DM + kt * 64,
                        &Aa[buf][(w * 32 + j * 8) * 64]);
    };
    auto STAGE_B = [&](int buf, int kt) {
        #pragma unroll
        for (int j = 0; j < 3; ++j)
            gload_lds16(gB0 + (size_t)j * 8 * DM + kt * 64,
                        &Bb[buf][(w * 24 + j * 8) * 64]);
    };

    // ---- reg-staging path (BNA>0): linear global load + swizzled ds_write ----
    const int rRow0 = w * 32 + (lane >> 3);                 // staged row (j*8 added)
    const unsigned short* gAr = A + (size_t)(m0 + rRow0) * DM + (lane & 7) * 8;
    const int wrswz = (lane >> 3) << 4;                     // (row&7)<<4
    ushort8 aldr[4];

    auto ALOAD = [&](int t) {
        #pragma unroll
        for (int j = 0; j < 4; ++j)
            aldr[j] = *(const ushort8*)(gAr + (size_t)j * 8 * DM + t * 64);
    };
    auto XFORM = [&](int t, int tb) {
        const int k0 = t * 64 + (lane & 7) * 8;
        f32x4 sa = *(const f32x4*)(ssA + k0);
        f32x4 sb = *(const f32x4*)(ssA + k0 + 4);
        f32x4 ha = *(const f32x4*)(ssA + DM + k0);
        f32x4 hb = *(const f32x4*)(ssA + DM + k0 + 4);
        #pragma unroll
        for (int j = 0; j < 4; ++j) {
            int row = rRow0 + j * 8;
            f32x4 pa, pb;
            if (BNA == 2) {
                pa = *(const f32x4*)(pos + row * DM + k0);
                pb = *(const f32x4*)(pos + row * DM + k0 + 4);
            }
            ushort8 u = aldr[j];
            ushort8 o;
            #pragma unroll
            for (int e = 0; e < 8; ++e) {
                float f = bf2f(u[e]);
                float sc = (e < 4) ? sa[e] : sb[e - 4];
                float sh = (e < 4) ? ha[e] : hb[e - 4];
                float y = fmaxf(fmaf(sc, f, sh), 0.0f);
                if (BNA == 2) {
                    float pv = (e < 4) ? pa[e] : pb[e - 4];
                    y = fmaxf(y + pv, 0.0f);
                }
                o[e] = f2bf(y);
            }
            *(ushort8*)((char*)Aa + (size_t)tb * (BM*64*2) + row * 128 +
                        (((lane & 7) * 16) ^ wrswz)) = o;
        }
    };

    const int frow = lane & 15;
    const int fq16 = (lane >> 4) * 16;
    const int rswz = (lane & 7) << 4;

    f32x4 acc[8][3] = {};
    short8 breg[3];

    // ---- prologue ----
    if (BNA == 0) {
        STAGE_A(0, 0);
        STAGE_B(0, 0);
        STAGE_A(1, 1);
        VM4
        BARR
    } else {
        ALOAD(0); XFORM(0, 0);
        ALOAD(1); XFORM(1, 1);
        STAGE_B(0, 0);
        VM0
        LGKM0
        BARR
    }

    if (BNA == 0) {
        #pragma unroll
        for (int kt = 0; kt < NKT3; ++kt) {
            const int ab = kt % 3, bb = kt & 1;
            PH(ab, bb, 0, 0, 1, { if (kt < 11) STAGE_B((kt + 1) & 1, kt + 1); }, {})
            PH(ab, bb, 1, 0, 0, { if (kt < 10) STAGE_A((kt + 2) % 3, kt + 2); }, {})
            PH(ab, bb, 0, 1, 1, {}, {})
            if (kt < 10)       { PH(ab, bb, 1, 1, 0, {}, { VM4 }) }
            else if (kt == 10) { PH(ab, bb, 1, 1, 0, {}, { VM0 }) }
            else               { PH(ab, bb, 1, 1, 0, {}, {}) }
        }
    } else {
        #pragma unroll 3
        for (int kt = 0; kt < NKT3; ++kt) {
            const int ab = kt % 3, bb = kt & 1;
            const int ab1 = (ab == 2) ? 0 : ab + 1;
            PH(ab, bb, 0, 0, 1, { if (kt < 11) STAGE_B((kt + 1) & 1, kt + 1); }, {})
            PH(ab, bb, 1, 0, 0, { if (kt >= 1 && kt < 11) XFORM(kt + 1, ab1); },
                                { if (kt >= 1 && kt < 11) LGKM0 })
            PH(ab, bb, 0, 1, 1, {}, {})
            PH(ab, bb, 1, 1, 0, {}, { if (kt < 11) VM0
                                      if (kt < 10) ALOAD(kt + 2); })
        }
    }

    // ---- epilogue ----
    const int crow = (lane >> 4) * 4;
    const int ccol = lane & 15;
    const int nbase = n0 + wc * 48;

    float bv[3];
    #pragma unroll
    for (int j = 0; j < 3; ++j) bv[j] = bias[nbase + j * 16 + ccol];

    if (EPI == 0) {
        unsigned short* O = (unsigned short*)outp;
        #pragma unroll
        for (int mi = 0; mi < 8; ++mi) {
            #pragma unroll
            for (int r = 0; r < 4; ++r) {
                int m = m0 + wr * 128 + mi * 16 + crow + r;
                unsigned short* orow = O + (size_t)m * DM + nbase + ccol;
                #pragma unroll
                for (int j = 0; j < 3; ++j)
                    orow[j * 16] = f2bf(fmaxf(acc[mi][j][r] + bv[j], 0.0f));
            }
        }
    }

    if (EPI == 2) {
        float* O = (float*)outp;
        #pragma unroll
        for (int mi = 0; mi < 8; ++mi) {
            #pragma unroll
            for (int r = 0; r < 4; ++r) {
                int m = m0 + wr * 128 + mi * 16 + crow + r;
                int mo = (m & ~255) | invp[m];
                float* orow = O + (size_t)mo * DM + nbase + ccol;
                #pragma unroll
                for (int j = 0; j < 3; ++j)
                    orow[j * 16] = acc[mi][j][r] + bv[j];
            }
        }
    }

    if (EPI == 1) {
        unsigned short* O = (unsigned short*)outp;
        #pragma unroll
        for (int mi = 0; mi < 8; ++mi) {
            #pragma unroll
            for (int r = 0; r < 4; ++r) {
                int m = m0 + wr * 128 + mi * 16 + crow + r;
                unsigned short* orow = O + (size_t)m * DM + nbase + ccol;
                #pragma unroll
                for (int j = 0; j < 3; ++j)
                    orow[j * 16] = f2bf(acc[mi][j][r] + bv[j]);
            }
        }
        // deterministic BN column partials (this wave: 128 rows x 48 cols)
        #pragma unroll
        for (int j = 0; j < 3; ++j) {
            float s = 0.f, q = 0.f;
            #pragma unroll
            for (int mi = 0; mi < 8; ++mi)
                #pragma unroll
                for (int r = 0; r < 4; ++r) {
                    float v = acc[mi][j][r] + bv[j];
                    s += v; q += v * v;
                }
            s += __shfl_xor(s, 16); s += __shfl_xor(s, 32);
            q += __shfl_xor(q, 16); q += __shfl_xor(q, 32);
            if (lane < 16) {
                int c  = nbase + j * 16 + lane;
                int ri = tileM * 2 + wr;
                bnpart[(size_t)c * 128 + ri]        = s;
                bnpart[QOFF + (size_t)c * 128 + ri] = q;
            }
        }
    }
}

// ---------------- BN finalize: reduce 128 partials -> scale/shift ----------------
__global__ void bn_stats(const float* __restrict__ part, const float* __restrict__ gamma,
                         const float* __restrict__ beta, float* __restrict__ ss)
{
    int c = blockIdx.x * 256 + threadIdx.x;   // 768
    const float* ps = part + (size_t)c * 128;
    const float* pq = part + QOFF + (size_t)c * 128;
    float s = 0.f, q = 0.f;
    #pragma unroll 8
    for (int i = 0; i < 128; ++i) { s += ps[i]; q += pq[i]; }
    float mu  = s * (1.0f / 16384.0f);
    float var = q * (1.0f / 16384.0f) - mu * mu;
    float scale = rsqrtf(var + 1e-5f) * gamma[c];
    ss[c] = scale;
    ss[DM + c] = beta[c] - mu * scale;
}

extern "C" void kernel_launch(void* const* d_in, const int* in_sizes, int n_in,
                              void* d_out, int out_size, void* d_ws, size_t ws_size,
                              hipStream_t stream)
{
    (void)in_sizes; (void)n_in; (void)out_size; (void)ws_size;

    const float* x       = (const float*)d_in[0];
    const float* conv0_w = (const float*)d_in[1];
    const float* conv0_b = (const float*)d_in[2];
    const float* w1      = (const float*)d_in[3];
    const float* b1      = (const float*)d_in[4];
    const float* gamma   = (const float*)d_in[5];
    const float* beta    = (const float*)d_in[6];
    const float* pos     = (const float*)d_in[7];
    const float* mixer_w = (const float*)d_in[8];
    const float* mixer_b = (const float*)d_in[9];
    const int*   perm    = (const int*)d_in[10];

    // workspace layout (~53 MB)
    unsigned short* actA = (unsigned short*)d_ws;               // 16384*768 bf16
    unsigned short* actB = actA + (size_t)M_TOT * DM;           // 16384*768 bf16
    unsigned short* wA   = actB + (size_t)M_TOT * DM;           // 768*768
    unsigned short* wD   = wA + DM * DM;                        // 3*768*768
    unsigned short* wM   = wD + 3 * DM * DM;                    // 768*768
    float* bnpart = (float*)(wM + DM * DM);                     // 2*128*768 f32
    float* ss     = bnpart + 2 * 128 * DM;                      // 2*768
    int*   invp   = (int*)(ss + 2 * DM);                        // 16384

    prep<<<2944, 256, 0, stream>>>(conv0_w, w1, mixer_w, perm, wA, wD, wM, invp);
    im2col<<<12288, 256, 0, stream>>>(x, actA);

    // g0: patch embed h0 = relu(patches @ W0^T + b0) -> actB
    gemm8p<0, 0><<<256, 512, 0, stream>>>(actA, wA, conv0_b, actB, nullptr,
                                          nullptr, nullptr, nullptr);
    // g1: h1 = h0 @ w1[0]^T + b1[0] -> actA (+ partials)
    gemm8p<1, 0><<<256, 512, 0, stream>>>(actB, wD + 0 * (size_t)DM * DM, b1 + 0 * DM,
                                          actA, nullptr, bnpart, nullptr, nullptr);
    bn_stats<<<3, 256, 0, stream>>>(bnpart, gamma + 0 * DM, beta + 0 * DM, ss);
    // g2: h2 = relu(BN0(h1)) @ w1[1]^T + b1[1] -> actB (+ partials)
    gemm8p<1, 1><<<256, 512, 0, stream>>>(actA, wD + 1 * (size_t)DM * DM, b1 + 1 * DM,
                                          actB, nullptr, bnpart, ss, nullptr);
    bn_stats<<<3, 256, 0, stream>>>(bnpart, gamma + 1 * DM, beta + 1 * DM, ss);
    // g3: h3 = relu(BN1(h2)) @ w1[2]^T + b1[2] -> actA (+ partials)
    gemm8p<1, 1><<<256, 512, 0, stream>>>(actB, wD + 2 * (size_t)DM * DM, b1 + 2 * DM,
                                          actA, nullptr, bnpart, ss, nullptr);
    bn_stats<<<3, 256, 0, stream>>>(bnpart, gamma + 2 * DM, beta + 2 * DM, ss);
    // mixer: out = relu(relu(BN2(h3)) + pos) @ mixer_w^T + b, perm-scattered f32
    gemm8p<2, 2><<<256, 512, 0, stream>>>(actA, wM, mixer_b, d_out, invp,
                                          nullptr, ss, pos);
}

// Round 6
// 207.407 us; speedup vs baseline: 2.2590x; 1.0219x over previous
//
#include <hip/hip_runtime.h>
#include <hip/hip_bf16.h>
#include <stdint.h>

#define M_TOT 16384     // B*P = 64*256
#define DM 768
#define BM 256
#define BN 192
#define NKT3 12         // K / 64
#define QOFF (128 * DM) // sumsq offset in bnpart (floats)

typedef __attribute__((ext_vector_type(4))) float f32x4;
typedef __attribute__((ext_vector_type(8))) short short8;
typedef __attribute__((ext_vector_type(8))) unsigned short ushort8;
typedef __attribute__((ext_vector_type(4))) unsigned short ushort4v;

__device__ __forceinline__ unsigned short f2bf(float f) {
    union { float f; unsigned u; } v; v.f = f;
    unsigned r = v.u + 0x7fffu + ((v.u >> 16) & 1u);
    return (unsigned short)(r >> 16);
}
__device__ __forceinline__ float bf2f(unsigned short h) {
    union { unsigned u; float f; } v; v.u = ((unsigned)h) << 16;
    return v.f;
}

__device__ __forceinline__ void gload_lds16(const unsigned short* g, unsigned short* l) {
    __builtin_amdgcn_global_load_lds(
        (const __attribute__((address_space(1))) void*)g,
        (__attribute__((address_space(3))) void*)l, 16, 0, 0);
}

// ---------------- prep + im2col fused in ONE launch ----------------
__global__ __launch_bounds__(256)
void prepim(const float* __restrict__ cw, const float* __restrict__ w1,
            const float* __restrict__ mw, const int* __restrict__ perm,
            const float* __restrict__ x,
            unsigned short* __restrict__ wA, unsigned short* __restrict__ wD,
            unsigned short* __restrict__ wM, int* __restrict__ invp,
            unsigned short* __restrict__ patches)
{
    int b = blockIdx.x;
    if (b < 12288) {
        // im2col: x[B,3,256,256] -> patches[16384,768] bf16
        int t = b * 256 + threadIdx.x;     // 3,145,728 total (4 floats each)
        int bp = t / 192;
        int q  = t - bp * 192;
        int c   = q >> 6;
        int kh  = (q >> 2) & 15;
        int kw0 = (q & 3) << 2;
        int bb = bp >> 8, p = bp & 255;
        int ph = p >> 4, pw = p & 15;
        const float* src = x + ((((size_t)bb * 3 + c) * 256 + ph * 16 + kh) * 256 + pw * 16 + kw0);
        f32x4 v = *(const f32x4*)src;
        ushort4v o;
        o.x = f2bf(v.x); o.y = f2bf(v.y); o.z = f2bf(v.z); o.w = f2bf(v.w);
        *(ushort4v*)(patches + (size_t)bp * DM + (q << 2)) = o;
    } else if (b < 12288 + 2880) {
        int i = (b - 12288) * 256 + threadIdx.x;   // 737280 vec4 groups
        const float* src; unsigned short* dst; int off;
        if (i < 147456)              { src = cw; dst = wA; off = i; }
        else if (i < 147456+442368)  { src = w1; dst = wD; off = i - 147456; }
        else                         { src = mw; dst = wM; off = i - 589824; }
        f32x4 v = ((const f32x4*)src)[off];
        ushort4v o;
        o.x = f2bf(v.x); o.y = f2bf(v.y); o.z = f2bf(v.z); o.w = f2bf(v.w);
        ((ushort4v*)dst)[off] = o;
    } else {
        int i = (b - 12288 - 2880) * 256 + threadIdx.x;  // 16384
        int bb = i >> 8;
        invp[(bb << 8) + perm[i]] = i & 255;
    }
}

// =====================================================================
// GEMM: out[M,768] = T(A)[M,768] * Bw[768,768]^T + bias
//   T = identity        (BNA=0, A staged via global_load_lds)
//   T = relu(scl*a+shf) (BNA=1, reg-staged, fused BN apply)
// BM=256 x BN=192, BK=64, 8 waves (2M x 4N), wave tile 128x48.
// EPI 0: relu->bf16 ; EPI 1: ->bf16 + BN column partials ; EPI 2: perm-scatter->f32
// =====================================================================
#define VM4  asm volatile("s_waitcnt vmcnt(4)" ::: "memory");
#define VM0  asm volatile("s_waitcnt vmcnt(0)" ::: "memory");
#define LGKM0 asm volatile("s_waitcnt lgkmcnt(0)" ::: "memory");
#define BARR asm volatile("s_barrier" ::: "memory");

// phase: [opt B-frag loads] + A-frag loads + PRE + MFMA(12) + POST + barrier
#define PH(AB, BB, MH, KS, LOADB, PRE, POST)                                     \
  {                                                                              \
    if (LOADB) {                                                                 \
      _Pragma("unroll")                                                          \
      for (int j = 0; j < 3; ++j)                                                \
        breg[j] = *(const short8*)((const char*)Bb + (size_t)(BB) * (BN*64*2) +  \
                  (wc * 48 + j * 16 + frow) * 128 + (((KS) * 64 + fq16) ^ rswz));\
    }                                                                            \
    short8 af[4];                                                                \
    _Pragma("unroll")                                                            \
    for (int i = 0; i < 4; ++i)                                                  \
      af[i] = *(const short8*)((const char*)Aa + (size_t)(AB) * (BM*64*2) +      \
              (wr * 128 + (MH) * 64 + i * 16 + frow) * 128 +                     \
              (((KS) * 64 + fq16) ^ rswz));                                      \
    PRE;                                                                         \
    __builtin_amdgcn_s_setprio(1);                                               \
    _Pragma("unroll")                                                            \
    for (int i = 0; i < 4; ++i)                                                  \
      _Pragma("unroll")                                                          \
      for (int j = 0; j < 3; ++j)                                                \
        acc[(MH) * 4 + i][j] = __builtin_amdgcn_mfma_f32_16x16x32_bf16(          \
            af[i], breg[j], acc[(MH) * 4 + i][j], 0, 0, 0);                      \
    __builtin_amdgcn_s_setprio(0);                                               \
    POST;                                                                        \
    BARR                                                                         \
  }

template<int EPI, int BNA>
__global__ __launch_bounds__(512, 2)
void gemm8p(const unsigned short* __restrict__ A,
            const unsigned short* __restrict__ Bw,
            const float* __restrict__ bias,
            void* __restrict__ outp,
            const int* __restrict__ invp,
            float* __restrict__ bnpart,
            const float* __restrict__ ssA)     // [scale 768 | shift 768] for A transform
{
    __shared__ unsigned short Aa[3][BM * 64];   // 3 x 32 KB
    __shared__ unsigned short Bb[2][BN * 64];   // 2 x 24 KB  (total 144 KB -> 1 block/CU)

    const int tid  = threadIdx.x;
    const int w    = tid >> 6;
    const int lane = tid & 63;
    const int wr = w >> 2, wc = w & 3;

    // bijective XCD swizzle over exactly 256 workgroups (32 per XCD)
    int bid = blockIdx.x;
    int nb  = (bid & 7) * 32 + (bid >> 3);
    const int tileM = nb >> 2, tileN = nb & 3;
    const int m0 = tileM * BM, n0 = tileN * BN;

    // ---- gload_lds staging (linear LDS dest + inverse-swizzled global src) ----
    const int sRow = lane >> 3;
    const int swzc = ((lane & 7) * 16) ^ ((sRow & 7) << 4);
    const unsigned short* gA0 = A  + (size_t)(m0 + w * 32 + sRow) * DM + (swzc >> 1);
    const unsigned short* gB0 = Bw + (size_t)(n0 + w * 24 + sRow) * DM + (swzc >> 1);

    auto STAGE_A = [&](int buf, int kt) {
        #pragma unroll
        for (int j = 0; j < 4; ++j)
            gload_lds16(gA0 + (size_t)j * 8 * DM + kt * 64,
                        &Aa[buf][(w * 32 + j * 8) * 64]);
    };
    auto STAGE_B = [&](int buf, int kt) {
        #pragma unroll
        for (int j = 0; j < 3; ++j)
            gload_lds16(gB0 + (size_t)j * 8 * DM + kt * 64,
                        &Bb[buf][(w * 24 + j * 8) * 64]);
    };

    // ---- reg-staging path (BNA=1): linear global load + swizzled ds_write ----
    const int rRow0 = w * 32 + (lane >> 3);
    const unsigned short* gAr = A + (size_t)(m0 + rRow0) * DM + (lane & 7) * 8;
    const int wrswz = (lane >> 3) << 4;
    ushort8 aldr[4];

    auto ALOAD = [&](int t) {
        #pragma unroll
        for (int j = 0; j < 4; ++j)
            aldr[j] = *(const ushort8*)(gAr + (size_t)j * 8 * DM + t * 64);
    };
    auto XFORM = [&](int t, int tb) {
        const int k0 = t * 64 + (lane & 7) * 8;
        f32x4 sa = *(const f32x4*)(ssA + k0);
        f32x4 sb = *(const f32x4*)(ssA + k0 + 4);
        f32x4 ha = *(const f32x4*)(ssA + DM + k0);
        f32x4 hb = *(const f32x4*)(ssA + DM + k0 + 4);
        #pragma unroll
        for (int j = 0; j < 4; ++j) {
            int row = rRow0 + j * 8;
            ushort8 u = aldr[j];
            ushort8 o;
            #pragma unroll
            for (int e = 0; e < 8; ++e) {
                float f = bf2f(u[e]);
                float sc = (e < 4) ? sa[e] : sb[e - 4];
                float sh = (e < 4) ? ha[e] : hb[e - 4];
                o[e] = f2bf(fmaxf(fmaf(sc, f, sh), 0.0f));
            }
            *(ushort8*)((char*)Aa + (size_t)tb * (BM*64*2) + row * 128 +
                        (((lane & 7) * 16) ^ wrswz)) = o;
        }
    };

    const int frow = lane & 15;
    const int fq16 = (lane >> 4) * 16;
    const int rswz = (lane & 7) << 4;

    f32x4 acc[8][3] = {};
    short8 breg[3];

    // ---- prologue ----
    if (BNA == 0) {
        STAGE_A(0, 0);
        STAGE_B(0, 0);
        STAGE_A(1, 1);
        VM4
        BARR
    } else {
        ALOAD(0); XFORM(0, 0);
        ALOAD(1); XFORM(1, 1);
        STAGE_B(0, 0);
        VM0
        LGKM0
        BARR
    }

    if (BNA == 0) {
        #pragma unroll
        for (int kt = 0; kt < NKT3; ++kt) {
            const int ab = kt % 3, bb = kt & 1;
            PH(ab, bb, 0, 0, 1, { if (kt < 11) STAGE_B((kt + 1) & 1, kt + 1); }, {})
            PH(ab, bb, 1, 0, 0, { if (kt < 10) STAGE_A((kt + 2) % 3, kt + 2); }, {})
            PH(ab, bb, 0, 1, 1, {}, {})
            if (kt < 10)       { PH(ab, bb, 1, 1, 0, {}, { VM4 }) }
            else if (kt == 10) { PH(ab, bb, 1, 1, 0, {}, { VM0 }) }
            else               { PH(ab, bb, 1, 1, 0, {}, {}) }
        }
    } else {
        #pragma unroll 3
        for (int kt = 0; kt < NKT3; ++kt) {
            const int ab = kt % 3, bb = kt & 1;
            const int ab1 = (ab == 2) ? 0 : ab + 1;
            PH(ab, bb, 0, 0, 1, { if (kt < 11) STAGE_B((kt + 1) & 1, kt + 1); }, {})
            PH(ab, bb, 1, 0, 0, { if (kt >= 1 && kt < 11) XFORM(kt + 1, ab1); },
                                { if (kt >= 1 && kt < 11) LGKM0 })
            PH(ab, bb, 0, 1, 1, {}, {})
            PH(ab, bb, 1, 1, 0, {}, { if (kt < 11) VM0
                                      if (kt < 10) ALOAD(kt + 2); })
        }
    }

    // ---- epilogue ----
    const int crow = (lane >> 4) * 4;
    const int ccol = lane & 15;
    const int nbase = n0 + wc * 48;

    float bv[3];
    #pragma unroll
    for (int j = 0; j < 3; ++j) bv[j] = bias[nbase + j * 16 + ccol];

    if (EPI == 0) {
        unsigned short* O = (unsigned short*)outp;
        #pragma unroll
        for (int mi = 0; mi < 8; ++mi) {
            #pragma unroll
            for (int r = 0; r < 4; ++r) {
                int m = m0 + wr * 128 + mi * 16 + crow + r;
                unsigned short* orow = O + (size_t)m * DM + nbase + ccol;
                #pragma unroll
                for (int j = 0; j < 3; ++j)
                    orow[j * 16] = f2bf(fmaxf(acc[mi][j][r] + bv[j], 0.0f));
            }
        }
    }

    if (EPI == 2) {
        float* O = (float*)outp;
        #pragma unroll
        for (int mi = 0; mi < 8; ++mi) {
            #pragma unroll
            for (int r = 0; r < 4; ++r) {
                int m = m0 + wr * 128 + mi * 16 + crow + r;
                int mo = (m & ~255) | invp[m];
                float* orow = O + (size_t)mo * DM + nbase + ccol;
                #pragma unroll
                for (int j = 0; j < 3; ++j)
                    orow[j * 16] = acc[mi][j][r] + bv[j];
            }
        }
    }

    if (EPI == 1) {
        unsigned short* O = (unsigned short*)outp;
        #pragma unroll
        for (int mi = 0; mi < 8; ++mi) {
            #pragma unroll
            for (int r = 0; r < 4; ++r) {
                int m = m0 + wr * 128 + mi * 16 + crow + r;
                unsigned short* orow = O + (size_t)m * DM + nbase + ccol;
                #pragma unroll
                for (int j = 0; j < 3; ++j)
                    orow[j * 16] = f2bf(acc[mi][j][r] + bv[j]);
            }
        }
        // deterministic BN column partials (this wave: 128 rows x 48 cols)
        #pragma unroll
        for (int j = 0; j < 3; ++j) {
            float s = 0.f, q = 0.f;
            #pragma unroll
            for (int mi = 0; mi < 8; ++mi)
                #pragma unroll
                for (int r = 0; r < 4; ++r) {
                    float v = acc[mi][j][r] + bv[j];
                    s += v; q += v * v;
                }
            s += __shfl_xor(s, 16); s += __shfl_xor(s, 32);
            q += __shfl_xor(q, 16); q += __shfl_xor(q, 32);
            if (lane < 16) {
                int c  = nbase + j * 16 + lane;
                int ri = tileM * 2 + wr;
                bnpart[(size_t)c * 128 + ri]        = s;
                bnpart[QOFF + (size_t)c * 128 + ri] = q;
            }
        }
    }
}

// ---------------- BN finalize: reduce 128 partials -> scale/shift ----------------
__global__ void bn_stats(const float* __restrict__ part, const float* __restrict__ gamma,
                         const float* __restrict__ beta, float* __restrict__ ss)
{
    int c = blockIdx.x * 256 + threadIdx.x;   // 768
    const float* ps = part + (size_t)c * 128;
    const float* pq = part + QOFF + (size_t)c * 128;
    float s = 0.f, q = 0.f;
    #pragma unroll 8
    for (int i = 0; i < 128; ++i) { s += ps[i]; q += pq[i]; }
    float mu  = s * (1.0f / 16384.0f);
    float var = q * (1.0f / 16384.0f) - mu * mu;
    float scale = rsqrtf(var + 1e-5f) * gamma[c];
    ss[c] = scale;
    ss[DM + c] = beta[c] - mu * scale;
}

// ---------------- BN apply + pos + relu (mixer input) ----------------
__global__ __launch_bounds__(256)
void bnpos_apply(const unsigned short* __restrict__ hin, const float* __restrict__ ss,
                 const float* __restrict__ pos, unsigned short* __restrict__ hout)
{
    __shared__ float sc[DM], sh[DM];
    const int t = threadIdx.x;
    #pragma unroll
    for (int i = 0; i < 3; ++i) {
        sc[t + i * 256] = ss[t + i * 256];
        sh[t + i * 256] = ss[DM + t + i * 256];
    }
    __syncthreads();

    int g = blockIdx.x * 256 + t;           // 16384*96 vec8 groups
    int row = g / 96;
    int c0 = (g - row * 96) * 8;
    const short8 v = *(const short8*)(hin + (size_t)row * DM + c0);
    short8 o;
    #pragma unroll
    for (int e = 0; e < 8; ++e) {
        float xv = bf2f((unsigned short)v[e]);
        float y = fmaxf(xv * sc[c0 + e] + sh[c0 + e], 0.0f);
        y = fmaxf(y + pos[(row & 255) * DM + c0 + e], 0.0f);
        o[e] = (short)f2bf(y);
    }
    *(short8*)(hout + (size_t)row * DM + c0) = o;
}

extern "C" void kernel_launch(void* const* d_in, const int* in_sizes, int n_in,
                              void* d_out, int out_size, void* d_ws, size_t ws_size,
                              hipStream_t stream)
{
    (void)in_sizes; (void)n_in; (void)out_size; (void)ws_size;

    const float* x       = (const float*)d_in[0];
    const float* conv0_w = (const float*)d_in[1];
    const float* conv0_b = (const float*)d_in[2];
    const float* w1      = (const float*)d_in[3];
    const float* b1      = (const float*)d_in[4];
    const float* gamma   = (const float*)d_in[5];
    const float* beta    = (const float*)d_in[6];
    const float* pos     = (const float*)d_in[7];
    const float* mixer_w = (const float*)d_in[8];
    const float* mixer_b = (const float*)d_in[9];
    const int*   perm    = (const int*)d_in[10];

    // workspace layout (~53 MB)
    unsigned short* actA = (unsigned short*)d_ws;               // 16384*768 bf16
    unsigned short* actB = actA + (size_t)M_TOT * DM;           // 16384*768 bf16
    unsigned short* wA   = actB + (size_t)M_TOT * DM;           // 768*768
    unsigned short* wD   = wA + DM * DM;                        // 3*768*768
    unsigned short* wM   = wD + 3 * DM * DM;                    // 768*768
    float* bnpart = (float*)(wM + DM * DM);                     // 2*128*768 f32
    float* ss     = bnpart + 2 * 128 * DM;                      // 2*768
    int*   invp   = (int*)(ss + 2 * DM);                        // 16384

    // prep (weights->bf16, invperm) + im2col, single launch
    prepim<<<15232, 256, 0, stream>>>(conv0_w, w1, mixer_w, perm, x,
                                      wA, wD, wM, invp, actA);

    // g0: patch embed h0 = relu(patches @ W0^T + b0) -> actB
    gemm8p<0, 0><<<256, 512, 0, stream>>>(actA, wA, conv0_b, actB, nullptr,
                                          nullptr, nullptr);
    // g1: h1 = h0 @ w1[0]^T + b1[0] -> actA (+ partials)
    gemm8p<1, 0><<<256, 512, 0, stream>>>(actB, wD + 0 * (size_t)DM * DM, b1 + 0 * DM,
                                          actA, nullptr, bnpart, nullptr);
    bn_stats<<<3, 256, 0, stream>>>(bnpart, gamma + 0 * DM, beta + 0 * DM, ss);
    // g2: h2 = relu(BN0(h1)) @ w1[1]^T + b1[1] -> actB (+ partials)
    gemm8p<1, 1><<<256, 512, 0, stream>>>(actA, wD + 1 * (size_t)DM * DM, b1 + 1 * DM,
                                          actB, nullptr, bnpart, ss);
    bn_stats<<<3, 256, 0, stream>>>(bnpart, gamma + 1 * DM, beta + 1 * DM, ss);
    // g3: h3 = relu(BN1(h2)) @ w1[2]^T + b1[2] -> actA (+ partials)
    gemm8p<1, 1><<<256, 512, 0, stream>>>(actB, wD + 2 * (size_t)DM * DM, b1 + 2 * DM,
                                          actA, nullptr, bnpart, ss);
    bn_stats<<<3, 256, 0, stream>>>(bnpart, gamma + 2 * DM, beta + 2 * DM, ss);
    // mixer input: relu(relu(BN2(h3)) + pos) -> actB
    bnpos_apply<<<6144, 256, 0, stream>>>(actA, ss, pos, actB);
    // mixer: out = actB @ mixer_w^T + b, perm-scattered f32 (proven BNA=0 path)
    gemm8p<2, 0><<<256, 512, 0, stream>>>(actB, wM, mixer_b, d_out, invp,
                                          nullptr, nullptr);
}